// Round 1
// 153.130 us; speedup vs baseline: 1.0094x; 1.0094x over previous
//
#include <hip/hip_runtime.h>

#define BINS 4096      // 16^3
#define WORDS 2048     // u16-packed partials: 2 bins per u32 word
#define H_GRID 1024
#define H_BLOCK 512    // 8 waves/block, 4 blocks/CU -> 32 waves/CU (100% occ)
#define CHUNKS 16      // K2 row-chunks: 1024 rows / 16 = 64 rows per chunk

__device__ __forceinline__ int qz(float c) {
    // matches: clip((c * 15.0f).astype(int32), 0, 15); trunc == floor for c >= 0
    int q = (int)(c * 15.0f);
    q = q < 0 ? 0 : q;
    q = q > 15 ? 15 : q;
    return q;
}

__device__ __forceinline__ int bin3(float r, float g, float b) {
    return (qz(r) << 8) | (qz(g) << 4) | qz(b);
}

// K1: per-block u32 LDS histogram (unpacked: no pack ALU on the hot path,
// no packed-halfword collision coupling), u16-packed coalesced flush.
// 1024 blocks x 512 thr = 2048 thr/CU = 32 waves/CU. Exactly 4 quads/thread.
// Per-block point count = 8388608/1024 = 8192 (+tail) < 65535: u16 flush safe.
__global__ __launch_bounds__(H_BLOCK, 8) void hist_partial_kernel(
        const float* __restrict__ src, unsigned int* __restrict__ partials,
        int n_pts) {
    __shared__ unsigned int lh[BINS];   // 16 KiB
    for (int i = threadIdx.x; i < BINS; i += H_BLOCK) lh[i] = 0;
    __syncthreads();

    const float4* __restrict__ src4 = (const float4*)src;
    const int n_quads = n_pts >> 2;
    const int tid = blockIdx.x * H_BLOCK + threadIdx.x;
    const int stride = gridDim.x * H_BLOCK;
    for (int q = tid; q < n_quads; q += stride) {
        float4 a = src4[3 * q + 0];
        float4 b = src4[3 * q + 1];
        float4 c = src4[3 * q + 2];
        atomicAdd(&lh[bin3(a.x, a.y, a.z)], 1u);
        atomicAdd(&lh[bin3(a.w, b.x, b.y)], 1u);
        atomicAdd(&lh[bin3(b.z, b.w, c.x)], 1u);
        atomicAdd(&lh[bin3(c.y, c.z, c.w)], 1u);
    }
    if (blockIdx.x == 0) {
        int tail = n_pts & 3;
        if ((int)threadIdx.x < tail) {
            int p = (n_quads << 2) + threadIdx.x;
            atomicAdd(&lh[bin3(src[3 * p], src[3 * p + 1], src[3 * p + 2])], 1u);
        }
    }
    __syncthreads();

    // pack pairs -> u16x2 and flush coalesced: 2048 words / 512 thr = 4 passes.
    // LDS reads at stride 2 = 2-way bank alias (free, m136).
    unsigned int* dst = partials + (size_t)blockIdx.x * WORDS;
#pragma unroll
    for (int p = 0; p < WORDS / H_BLOCK; ++p) {
        int w = threadIdx.x + p * H_BLOCK;
        dst[w] = lh[2 * w] | (lh[2 * w + 1] << 16);
    }
}

// K2: parallel column-sum of the 1024 u16 partial rows.
// Grid = 16 bin-groups x 16 row-chunks = 256 blocks x 256 threads.
// Each thread sums 64 u16s for one bin (coalesced: consecutive threads read
// consecutive u16s), writes g_part[chunk][bin] non-atomically.
__global__ __launch_bounds__(256) void reduce_kernel(
        const unsigned int* __restrict__ partials,
        unsigned int* __restrict__ g_part) {
    const int bin   = (blockIdx.x & 15) * 256 + threadIdx.x;
    const int chunk = blockIdx.x >> 4;
    const int r0    = chunk * (H_GRID / CHUNKS);
    const unsigned short* __restrict__ p16 = (const unsigned short*)partials;
    unsigned int s = 0;
#pragma unroll 16
    for (int r = 0; r < H_GRID / CHUNKS; ++r)
        s += (unsigned int)p16[(size_t)(r0 + r) * BINS + bin];
    g_part[chunk * BINS + bin] = s;
}

// K3: single block -- target hist in LDS, then L1 loss (f64, deterministic).
// Source bin totals = sum of the 16 chunk-partials.
__global__ __launch_bounds__(1024) void loss_kernel(
        const float* __restrict__ tgt, const unsigned int* __restrict__ g_part,
        float* __restrict__ out, int n_src, int n_tgt) {
    __shared__ unsigned int th[BINS];
    for (int i = threadIdx.x; i < BINS; i += 1024) th[i] = 0;
    __syncthreads();

    const float4* __restrict__ t4 = (const float4*)tgt;
    const int tq = n_tgt >> 2;
    for (int q = threadIdx.x; q < tq; q += 1024) {
        float4 a = t4[3 * q + 0];
        float4 b = t4[3 * q + 1];
        float4 c = t4[3 * q + 2];
        atomicAdd(&th[bin3(a.x, a.y, a.z)], 1u);
        atomicAdd(&th[bin3(a.w, b.x, b.y)], 1u);
        atomicAdd(&th[bin3(b.z, b.w, c.x)], 1u);
        atomicAdd(&th[bin3(c.y, c.z, c.w)], 1u);
    }
    {
        int tail = n_tgt & 3;
        if ((int)threadIdx.x < tail) {
            int p = (tq << 2) + threadIdx.x;
            atomicAdd(&th[bin3(tgt[3 * p], tgt[3 * p + 1], tgt[3 * p + 2])], 1u);
        }
    }
    __syncthreads();

    const double ns = (double)n_src + 1e-8;
    const double nt = (double)n_tgt + 1e-8;
    double acc = 0.0;
    for (int i = threadIdx.x; i < BINS; i += 1024) {
        unsigned int sv = 0;
#pragma unroll
        for (int c = 0; c < CHUNKS; ++c) sv += g_part[c * BINS + i];
        acc += fabs((double)sv / ns - (double)th[i] / nt);
    }

    for (int off = 32; off > 0; off >>= 1) acc += __shfl_down(acc, off);
    __shared__ double red[16];
    if ((threadIdx.x & 63) == 0) red[threadIdx.x >> 6] = acc;
    __syncthreads();
    if (threadIdx.x == 0) {
        double s = 0.0;
        for (int w = 0; w < 16; ++w) s += red[w];
        out[0] = (float)(s / (double)BINS);
    }
}

extern "C" void kernel_launch(void* const* d_in, const int* in_sizes, int n_in,
                              void* d_out, int out_size, void* d_ws, size_t ws_size,
                              hipStream_t stream) {
    const float* src = (const float*)d_in[0];
    const float* tgt = (const float*)d_in[1];
    const int n_src = in_sizes[0] / 3;
    const int n_tgt = in_sizes[1] / 3;

    unsigned int* partials = (unsigned int*)d_ws;                 // 1024*2048 u32 = 8 MB
    unsigned int* g_part   = partials + (size_t)H_GRID * WORDS;   // 16*4096 u32 = 256 KB

    hist_partial_kernel<<<H_GRID, H_BLOCK, 0, stream>>>(src, partials, n_src);
    reduce_kernel<<<16 * CHUNKS, 256, 0, stream>>>(partials, g_part);
    loss_kernel<<<1, 1024, 0, stream>>>(tgt, g_part, (float*)d_out, n_src, n_tgt);
}

// Round 2
// 152.467 us; speedup vs baseline: 1.0137x; 1.0043x over previous
//
#include <hip/hip_runtime.h>

#define BINS 4096      // 16^3
#define H_GRID 256     // 1 block/CU; occupancy A/B (r0 vs r1) showed K1 is read-BW-bound
#define H_BLOCK 1024   // 16 waves/CU

typedef float f4 __attribute__((ext_vector_type(4)));

__device__ __forceinline__ int qz(float c) {
    // matches: clip((c * 15.0f).astype(int32), 0, 15); trunc == floor for c >= 0
    int q = (int)(c * 15.0f);
    q = q < 0 ? 0 : q;
    q = q > 15 ? 15 : q;
    return q;
}

__device__ __forceinline__ int bin3(float r, float g, float b) {
    return (qz(r) << 8) | (qz(g) << 4) | qz(b);
}

// K0: zero the global source histogram AND build the target histogram.
// Single block; runs before K1 (stream order guarantees g_hist is zeroed
// before any K1 flush atomics execute).
__global__ __launch_bounds__(1024) void prep_kernel(
        const float* __restrict__ tgt, unsigned int* __restrict__ g_hist,
        unsigned int* __restrict__ th, int n_tgt) {
    __shared__ unsigned int lh[BINS];
    for (int i = threadIdx.x; i < BINS; i += 1024) {
        lh[i] = 0;
        g_hist[i] = 0;
    }
    __syncthreads();

    const f4* __restrict__ t4 = (const f4*)tgt;
    const int tq = n_tgt >> 2;
    for (int q = threadIdx.x; q < tq; q += 1024) {
        f4 a = t4[3 * q + 0];
        f4 b = t4[3 * q + 1];
        f4 c = t4[3 * q + 2];
        atomicAdd(&lh[bin3(a.x, a.y, a.z)], 1u);
        atomicAdd(&lh[bin3(a.w, b.x, b.y)], 1u);
        atomicAdd(&lh[bin3(b.z, b.w, c.x)], 1u);
        atomicAdd(&lh[bin3(c.y, c.z, c.w)], 1u);
    }
    {
        int tail = n_tgt & 3;
        if ((int)threadIdx.x < tail) {
            int p = (tq << 2) + threadIdx.x;
            atomicAdd(&lh[bin3(tgt[3 * p], tgt[3 * p + 1], tgt[3 * p + 2])], 1u);
        }
    }
    __syncthreads();
    for (int i = threadIdx.x; i < BINS; i += 1024) th[i] = lh[i];
}

// K1: per-block u32 LDS histogram of the source points, then device-scope
// atomic flush into g_hist. 256 blocks -> 1M flush atomics total (~256 per
// bin), ~2 us at L2. Nontemporal loads: 100 MB is streamed exactly once.
__global__ __launch_bounds__(H_BLOCK) void hist_kernel(
        const float* __restrict__ src, unsigned int* __restrict__ g_hist,
        int n_pts) {
    __shared__ unsigned int lh[BINS];   // 16 KiB
    for (int i = threadIdx.x; i < BINS; i += H_BLOCK) lh[i] = 0;
    __syncthreads();

    const f4* __restrict__ src4 = (const f4*)src;
    const int n_quads = n_pts >> 2;
    const int tid = blockIdx.x * H_BLOCK + threadIdx.x;
    const int stride = gridDim.x * H_BLOCK;
    for (int q = tid; q < n_quads; q += stride) {
        f4 a = __builtin_nontemporal_load(&src4[3 * q + 0]);
        f4 b = __builtin_nontemporal_load(&src4[3 * q + 1]);
        f4 c = __builtin_nontemporal_load(&src4[3 * q + 2]);
        atomicAdd(&lh[bin3(a.x, a.y, a.z)], 1u);
        atomicAdd(&lh[bin3(a.w, b.x, b.y)], 1u);
        atomicAdd(&lh[bin3(b.z, b.w, c.x)], 1u);
        atomicAdd(&lh[bin3(c.y, c.z, c.w)], 1u);
    }
    if (blockIdx.x == 0) {
        int tail = n_pts & 3;
        if ((int)threadIdx.x < tail) {
            int p = (n_quads << 2) + threadIdx.x;
            atomicAdd(&lh[bin3(src[3 * p], src[3 * p + 1], src[3 * p + 2])], 1u);
        }
    }
    __syncthreads();

    // flush: 4 bins per thread; skip empty bins (P(empty) ~ e^-8, negligible
    // divergence) to cut atomic traffic.
#pragma unroll
    for (int p = 0; p < BINS / H_BLOCK; ++p) {
        int i = threadIdx.x + p * H_BLOCK;
        unsigned int v = lh[i];
        if (v) atomicAdd(&g_hist[i], v);
    }
}

// K2: single block -- pure L1 loss from the two 16 KB histograms (f64,
// deterministic).
__global__ __launch_bounds__(1024) void loss_kernel(
        const unsigned int* __restrict__ g_hist,
        const unsigned int* __restrict__ th, float* __restrict__ out,
        int n_src, int n_tgt) {
    const double ns = (double)n_src + 1e-8;
    const double nt = (double)n_tgt + 1e-8;
    double acc = 0.0;
    for (int i = threadIdx.x; i < BINS; i += 1024)
        acc += fabs((double)g_hist[i] / ns - (double)th[i] / nt);

    for (int off = 32; off > 0; off >>= 1) acc += __shfl_down(acc, off);
    __shared__ double red[16];
    if ((threadIdx.x & 63) == 0) red[threadIdx.x >> 6] = acc;
    __syncthreads();
    if (threadIdx.x == 0) {
        double s = 0.0;
        for (int w = 0; w < 16; ++w) s += red[w];
        out[0] = (float)(s / (double)BINS);
    }
}

extern "C" void kernel_launch(void* const* d_in, const int* in_sizes, int n_in,
                              void* d_out, int out_size, void* d_ws, size_t ws_size,
                              hipStream_t stream) {
    const float* src = (const float*)d_in[0];
    const float* tgt = (const float*)d_in[1];
    const int n_src = in_sizes[0] / 3;
    const int n_tgt = in_sizes[1] / 3;

    unsigned int* g_hist = (unsigned int*)d_ws;   // 4096 u32 = 16 KB
    unsigned int* th     = g_hist + BINS;         // 4096 u32 = 16 KB

    prep_kernel<<<1, 1024, 0, stream>>>(tgt, g_hist, th, n_tgt);
    hist_kernel<<<H_GRID, H_BLOCK, 0, stream>>>(src, g_hist, n_src);
    loss_kernel<<<1, 1024, 0, stream>>>(g_hist, th, (float*)d_out, n_src, n_tgt);
}